// Round 1
// baseline (2995.086 us; speedup 1.0000x reference)
//
#include <hip/hip_runtime.h>
#include <math.h>

#define CN 32    // classes
#define DN 128   // feature dim

// ---------------- softmax over C per node: 32 threads/node ----------------
__global__ void k_softmax(const float* __restrict__ logits, float* __restrict__ probs, int N) {
    int t = blockIdx.x * blockDim.x + threadIdx.x;
    int node = t >> 5, c = t & 31;
    if (node >= N) return;
    float l = logits[node * CN + c];
    float m = l;
    #pragma unroll
    for (int o = 16; o; o >>= 1) m = fmaxf(m, __shfl_xor(m, o, 32));
    float e = __expf(l - m);
    float s = e;
    #pragma unroll
    for (int o = 16; o; o >>= 1) s += __shfl_xor(s, o, 32);
    probs[node * CN + c] = e / s;
}

// -------- edge scatter 1: sum_p[dst] += probs[src]; deg[dst] += 1 ---------
__global__ void k_scatter_probs(const int* __restrict__ src, const int* __restrict__ dst,
                                const float* __restrict__ probs,
                                float* __restrict__ sum_p, float* __restrict__ deg, int E) {
    int t = blockIdx.x * blockDim.x + threadIdx.x;
    int e = t >> 5, c = t & 31;
    if (e >= E) return;
    int s = src[e], d = dst[e];
    atomicAdd(&sum_p[(size_t)d * CN + c], probs[(size_t)s * CN + c]);
    if (c == 0) atomicAdd(&deg[d], 1.0f);
}

// -------- per-node f1 (KL), f2 (entropy) + global LN stats (double) -------
__global__ void k_f(const float* __restrict__ probs, const float* __restrict__ sum_p,
                    const float* __restrict__ deg, float* __restrict__ f1buf,
                    float* __restrict__ f2buf, double* __restrict__ stats, int N) {
    int i = blockIdx.x * blockDim.x + threadIdx.x;
    float f1 = 0.f, f2 = 0.f;
    if (i < N) {
        float dg = deg[i];
        if (dg > 0.f) {
            float inv = 1.0f / dg;   // dg >= 1 here, matches max(deg,1)
            const float4* p4 = (const float4*)(probs + (size_t)i * CN);
            const float4* s4 = (const float4*)(sum_p + (size_t)i * CN);
            #pragma unroll
            for (int q = 0; q < CN / 4; ++q) {
                float4 p = p4[q], sp = s4[q];
                float pv[4] = {p.x, p.y, p.z, p.w};
                float sv[4] = {sp.x, sp.y, sp.z, sp.w};
                #pragma unroll
                for (int k = 0; k < 4; ++k) {
                    float mp = sv[k] * inv;
                    float lm = logf(mp + 1e-9f);
                    f1 += pv[k] * (logf(pv[k] + 1e-9f) - lm);
                    f2 -= mp * lm;
                }
            }
        }
        f1buf[i] = f1;
        f2buf[i] = f2;
    }
    // block reduction of (f1, f1^2, f2, f2^2) in double
    double v0 = f1, v1 = (double)f1 * f1, v2 = f2, v3 = (double)f2 * f2;
    #pragma unroll
    for (int off = 32; off; off >>= 1) {
        v0 += __shfl_down(v0, off);
        v1 += __shfl_down(v1, off);
        v2 += __shfl_down(v2, off);
        v3 += __shfl_down(v3, off);
    }
    __shared__ double sh[4][4];
    int wave = threadIdx.x >> 6, lane = threadIdx.x & 63;
    if (lane == 0) { sh[0][wave] = v0; sh[1][wave] = v1; sh[2][wave] = v2; sh[3][wave] = v3; }
    __syncthreads();
    if (threadIdx.x == 0) {
        double a = 0, b = 0, c = 0, d = 0;
        #pragma unroll
        for (int w = 0; w < 4; ++w) { a += sh[0][w]; b += sh[1][w]; c += sh[2][w]; d += sh[3][w]; }
        atomicAdd(&stats[0], a);
        atomicAdd(&stats[1], b);
        atomicAdd(&stats[2], c);
        atomicAdd(&stats[3], d);
    }
}

// ---------------- per-node gating: z, gate = min(old_z, z) ----------------
__global__ void k_z(const float* __restrict__ f1buf, const float* __restrict__ f2buf,
                    const double* __restrict__ stats, const float* __restrict__ old_z,
                    const float* __restrict__ tau1, const float* __restrict__ tau2,
                    float* __restrict__ z_out, float* __restrict__ gate, int N) {
    int i = blockIdx.x * blockDim.x + threadIdx.x;
    if (i >= N) return;
    double invN = 1.0 / (double)N;
    float mu1 = (float)(stats[0] * invN);
    float var1 = (float)(stats[1] * invN) - mu1 * mu1;
    float is1 = rsqrtf(var1 + 1e-5f);
    float mu2 = (float)(stats[2] * invN);
    float var2 = (float)(stats[3] * invN) - mu2 * mu2;
    float is2 = rsqrtf(var2 + 1e-5f);
    float a = (f1buf[i] - mu1) * is1;
    float b = (f2buf[i] - mu2) * is2;
    // sigmoid(-(a - tau)) = 1 / (1 + exp(a - tau))
    float z = (1.f / (1.f + __expf(a - tau1[0]))) * (1.f / (1.f + __expf(b - tau2[0])));
    z_out[i] = z;
    gate[i] = fminf(old_z[i], z);
}

// -------- edge scatter 2: agg[dst] += h[src]  (agg lives in d_out) --------
__global__ void k_scatter_h(const int* __restrict__ src, const int* __restrict__ dst,
                            const float* __restrict__ h, float* __restrict__ agg, int E) {
    int t = blockIdx.x * blockDim.x + threadIdx.x;
    int e = t >> 5, q = t & 31;
    if (e >= E) return;
    int s = src[e], d = dst[e];
    float4 v = ((const float4*)(h + (size_t)s * DN))[q];
    float* ap = agg + (size_t)d * DN + q * 4;
    atomicAdd(ap + 0, v.x);
    atomicAdd(ap + 1, v.y);
    atomicAdd(ap + 2, v.z);
    atomicAdd(ap + 3, v.w);
}

// -------- epilogue: new_h = h + gate * relu(agg * norm), in-place ---------
__global__ void k_final(const float* __restrict__ h, const float* __restrict__ norm,
                        const float* __restrict__ gate, float* __restrict__ out, int N) {
    int t = blockIdx.x * blockDim.x + threadIdx.x;
    int i = t >> 5, q = t & 31;
    if (i >= N) return;
    float g = gate[i], nm = norm[i];
    float4 hv = ((const float4*)(h + (size_t)i * DN))[q];
    float4 av = ((float4*)(out + (size_t)i * DN))[q];
    float4 r;
    r.x = hv.x + g * fmaxf(av.x * nm, 0.f);
    r.y = hv.y + g * fmaxf(av.y * nm, 0.f);
    r.z = hv.z + g * fmaxf(av.z * nm, 0.f);
    r.w = hv.w + g * fmaxf(av.w * nm, 0.f);
    ((float4*)(out + (size_t)i * DN))[q] = r;
}

extern "C" void kernel_launch(void* const* d_in, const int* in_sizes, int n_in,
                              void* d_out, int out_size, void* d_ws, size_t ws_size,
                              hipStream_t stream) {
    const float* h      = (const float*)d_in[0];
    const float* logits = (const float*)d_in[1];
    const float* old_z  = (const float*)d_in[2];
    const float* norm   = (const float*)d_in[3];
    const float* tau1   = (const float*)d_in[4];
    const float* tau2   = (const float*)d_in[5];
    const int*   src    = (const int*)d_in[6];
    const int*   dst    = (const int*)d_in[7];
    const int N = in_sizes[2];   // old_z length
    const int E = in_sizes[6];   // src length

    float* out   = (float*)d_out;            // [N*DN] new_h, then [N] z
    float* z_out = out + (size_t)N * DN;

    // workspace layout: stats (4 doubles) | probs | sum_p | deg | f1 | f2 | gate
    char*   ws    = (char*)d_ws;
    double* stats = (double*)ws;
    float*  probs = (float*)(ws + 64);
    float*  sum_p = probs + (size_t)N * CN;
    float*  deg   = sum_p + (size_t)N * CN;
    float*  f1buf = deg + N;
    float*  f2buf = f1buf + N;
    float*  gate  = f2buf + N;

    hipMemsetAsync(stats, 0, 32, stream);
    hipMemsetAsync(sum_p, 0, ((size_t)N * CN + N) * sizeof(float), stream); // sum_p + deg
    hipMemsetAsync(out, 0, (size_t)N * DN * sizeof(float), stream);         // agg accumulator

    const int B = 256;
    int tn32 = N * CN;                       // N*32 threads
    k_softmax<<<(tn32 + B - 1) / B, B, 0, stream>>>(logits, probs, N);

    long long te = (long long)E * 32;
    k_scatter_probs<<<(int)((te + B - 1) / B), B, 0, stream>>>(src, dst, probs, sum_p, deg, E);

    k_f<<<(N + B - 1) / B, B, 0, stream>>>(probs, sum_p, deg, f1buf, f2buf, stats, N);
    k_z<<<(N + B - 1) / B, B, 0, stream>>>(f1buf, f2buf, stats, old_z, tau1, tau2, z_out, gate, N);

    k_scatter_h<<<(int)((te + B - 1) / B), B, 0, stream>>>(src, dst, h, out, E);

    int tnd = N * 32;                        // N * (DN/4) lanes of float4
    k_final<<<(tnd + B - 1) / B, B, 0, stream>>>(h, norm, gate, out, N);
}

// Round 2
// 952.758 us; speedup vs baseline: 3.1436x; 3.1436x over previous
//
#include <hip/hip_runtime.h>
#include <math.h>

#define CN 32    // classes
#define DN 128   // feature dim

// ---------------- softmax over C per node: 32 threads/node ----------------
__global__ void k_softmax(const float* __restrict__ logits, float* __restrict__ probs, int N) {
    int t = blockIdx.x * blockDim.x + threadIdx.x;
    int node = t >> 5, c = t & 31;
    if (node >= N) return;
    float l = logits[node * CN + c];
    float m = l;
    #pragma unroll
    for (int o = 16; o; o >>= 1) m = fmaxf(m, __shfl_xor(m, o, 32));
    float e = __expf(l - m);
    float s = e;
    #pragma unroll
    for (int o = 16; o; o >>= 1) s += __shfl_xor(s, o, 32);
    probs[node * CN + c] = e / s;
}

// ---------------- CSR build: histogram of dst ----------------
__global__ void k_hist(const int* __restrict__ dst, int* __restrict__ cnt, int E) {
    int e = blockIdx.x * blockDim.x + threadIdx.x;
    if (e < E) atomicAdd(&cnt[dst[e]], 1);
}

// per-256-block sums of cnt
__global__ void k_blocksum(const int* __restrict__ cnt, int* __restrict__ bsum, int N) {
    int i = blockIdx.x * 256 + threadIdx.x;
    int v = (i < N) ? cnt[i] : 0;
    #pragma unroll
    for (int o = 32; o; o >>= 1) v += __shfl_down(v, o, 64);
    __shared__ int sh[4];
    int wv = threadIdx.x >> 6, ln = threadIdx.x & 63;
    if (ln == 0) sh[wv] = v;
    __syncthreads();
    if (threadIdx.x == 0) bsum[blockIdx.x] = sh[0] + sh[1] + sh[2] + sh[3];
}

// single-block exclusive scan of block sums (NB <= 512)
__global__ void k_scanb(const int* __restrict__ bsum, int* __restrict__ bscan, int NB) {
    int t = threadIdx.x;
    int v = (t < NB) ? bsum[t] : 0;
    int incl = v;
    int ln = t & 63;
    #pragma unroll
    for (int o = 1; o < 64; o <<= 1) { int u = __shfl_up(incl, o, 64); if (ln >= o) incl += u; }
    __shared__ int wsum[8];
    int wv = t >> 6;
    if (ln == 63) wsum[wv] = incl;
    __syncthreads();
    int add = 0;
    for (int w = 0; w < wv; ++w) add += wsum[w];
    if (t < NB) bscan[t] = incl - v + add;
}

// per-element exclusive offsets = local scan + bscan[block]; also init cursors
__global__ void k_offsets(const int* __restrict__ cnt, const int* __restrict__ bscan,
                          int* __restrict__ off, int* __restrict__ cur, int N) {
    int i = blockIdx.x * 256 + threadIdx.x;
    int v = (i < N) ? cnt[i] : 0;
    int ln = threadIdx.x & 63, wv = threadIdx.x >> 6;
    int incl = v;
    #pragma unroll
    for (int o = 1; o < 64; o <<= 1) { int u = __shfl_up(incl, o, 64); if (ln >= o) incl += u; }
    __shared__ int wsum[4];
    if (ln == 63) wsum[wv] = incl;
    __syncthreads();
    int add = bscan[blockIdx.x];
    for (int w = 0; w < wv; ++w) add += wsum[w];
    if (i < N) { int ex = incl - v + add; off[i] = ex; cur[i] = ex; }
}

// bucket-fill edge sources by dst
__global__ void k_fill(const int* __restrict__ src, const int* __restrict__ dst,
                       int* __restrict__ cur, int* __restrict__ eidx, int E) {
    int e = blockIdx.x * blockDim.x + threadIdx.x;
    if (e >= E) return;
    int p = atomicAdd(&cur[dst[e]], 1);
    eidx[p] = src[e];
}

// ---- gather probs + KL/entropy + global LN stats: 32 threads/node ----
__global__ void k_probs_f(const float* __restrict__ probs, const int* __restrict__ off,
                          const int* __restrict__ cnt, const int* __restrict__ eidx,
                          float* __restrict__ f1buf, float* __restrict__ f2buf,
                          double* __restrict__ stats, int N) {
    int t = blockIdx.x * blockDim.x + threadIdx.x;
    int i = t >> 5, c = t & 31;
    float f1 = 0.f, f2 = 0.f;
    if (i < N) {
        int beg = off[i], dg = cnt[i];
        float sum = 0.f;
        for (int k = 0; k < dg; ++k) {
            int s = eidx[beg + k];
            sum += probs[(size_t)s * CN + c];
        }
        float f1c = 0.f, f2c = 0.f;
        if (dg > 0) {
            float p = probs[(size_t)i * CN + c];
            float mp = sum / (float)dg;
            float lm = logf(mp + 1e-9f);
            f1c = p * (logf(p + 1e-9f) - lm);
            f2c = -mp * lm;
        }
        #pragma unroll
        for (int o = 16; o; o >>= 1) { f1c += __shfl_xor(f1c, o, 32); f2c += __shfl_xor(f2c, o, 32); }
        if (c == 0) { f1buf[i] = f1c; f2buf[i] = f2c; f1 = f1c; f2 = f2c; }
    }
    // block reduction of (f1, f1^2, f2, f2^2) in double; nonzero only on c==0 lanes
    double v0 = f1, v1 = (double)f1 * f1, v2 = f2, v3 = (double)f2 * f2;
    #pragma unroll
    for (int o = 32; o; o >>= 1) {
        v0 += __shfl_down(v0, o, 64);
        v1 += __shfl_down(v1, o, 64);
        v2 += __shfl_down(v2, o, 64);
        v3 += __shfl_down(v3, o, 64);
    }
    __shared__ double sh[4][4];
    int wave = threadIdx.x >> 6, lane = threadIdx.x & 63;
    if (lane == 0) { sh[0][wave] = v0; sh[1][wave] = v1; sh[2][wave] = v2; sh[3][wave] = v3; }
    __syncthreads();
    if (threadIdx.x == 0) {
        double a = 0, b = 0, c2 = 0, d = 0;
        #pragma unroll
        for (int w = 0; w < 4; ++w) { a += sh[0][w]; b += sh[1][w]; c2 += sh[2][w]; d += sh[3][w]; }
        atomicAdd(&stats[0], a);
        atomicAdd(&stats[1], b);
        atomicAdd(&stats[2], c2);
        atomicAdd(&stats[3], d);
    }
}

// ---------------- per-node gating: z, gate = min(old_z, z) ----------------
__global__ void k_z(const float* __restrict__ f1buf, const float* __restrict__ f2buf,
                    const double* __restrict__ stats, const float* __restrict__ old_z,
                    const float* __restrict__ tau1, const float* __restrict__ tau2,
                    float* __restrict__ z_out, float* __restrict__ gate, int N) {
    int i = blockIdx.x * blockDim.x + threadIdx.x;
    if (i >= N) return;
    double invN = 1.0 / (double)N;
    float mu1 = (float)(stats[0] * invN);
    float var1 = (float)(stats[1] * invN) - mu1 * mu1;
    float is1 = rsqrtf(var1 + 1e-5f);
    float mu2 = (float)(stats[2] * invN);
    float var2 = (float)(stats[3] * invN) - mu2 * mu2;
    float is2 = rsqrtf(var2 + 1e-5f);
    float a = (f1buf[i] - mu1) * is1;
    float b = (f2buf[i] - mu2) * is2;
    float z = (1.f / (1.f + __expf(a - tau1[0]))) * (1.f / (1.f + __expf(b - tau2[0])));
    z_out[i] = z;
    gate[i] = fminf(old_z[i], z);
}

// ---- gather h + epilogue: one wave per node, float2 per lane ----
__global__ void k_gather_final(const float* __restrict__ h, const int* __restrict__ off,
                               const int* __restrict__ cnt, const int* __restrict__ eidx,
                               const float* __restrict__ gate, const float* __restrict__ norm,
                               float* __restrict__ out, int N) {
    int t = blockIdx.x * blockDim.x + threadIdx.x;
    int i = t >> 6, ln = t & 63;
    if (i >= N) return;
    int beg = off[i], dg = cnt[i];
    const float2* h2 = (const float2*)h;
    float ax = 0.f, ay = 0.f;
    int k = 0;
    for (; k + 1 < dg; k += 2) {
        int s0 = eidx[beg + k], s1 = eidx[beg + k + 1];
        float2 a = h2[(size_t)s0 * 64 + ln];
        float2 b = h2[(size_t)s1 * 64 + ln];
        ax += a.x + b.x; ay += a.y + b.y;
    }
    if (k < dg) {
        int s0 = eidx[beg + k];
        float2 a = h2[(size_t)s0 * 64 + ln];
        ax += a.x; ay += a.y;
    }
    float g = gate[i], nm = norm[i];
    float2 hv = h2[(size_t)i * 64 + ln];
    float2 r;
    r.x = hv.x + g * fmaxf(ax * nm, 0.f);
    r.y = hv.y + g * fmaxf(ay * nm, 0.f);
    ((float2*)out)[(size_t)i * 64 + ln] = r;
}

extern "C" void kernel_launch(void* const* d_in, const int* in_sizes, int n_in,
                              void* d_out, int out_size, void* d_ws, size_t ws_size,
                              hipStream_t stream) {
    const float* h      = (const float*)d_in[0];
    const float* logits = (const float*)d_in[1];
    const float* old_z  = (const float*)d_in[2];
    const float* norm   = (const float*)d_in[3];
    const float* tau1   = (const float*)d_in[4];
    const float* tau2   = (const float*)d_in[5];
    const int*   src    = (const int*)d_in[6];
    const int*   dst    = (const int*)d_in[7];
    const int N = in_sizes[2];   // old_z length
    const int E = in_sizes[6];   // src length

    float* out   = (float*)d_out;            // [N*DN] new_h, then [N] z
    float* z_out = out + (size_t)N * DN;

    // workspace layout
    char*   ws    = (char*)d_ws;
    double* stats = (double*)ws;                       // 4 doubles (pad to 64B)
    int*    cnt   = (int*)(ws + 64);                   // N
    int*    off   = cnt + N;                           // N
    int*    cur   = off + N;                           // N
    int*    bsum  = cur + N;                           // 512
    int*    bscan = bsum + 512;                        // 512
    int*    eidx  = bscan + 512;                       // E
    float*  probs = (float*)(eidx + E);                // N*CN
    float*  f1buf = probs + (size_t)N * CN;            // N
    float*  f2buf = f1buf + N;                         // N
    float*  gate  = f2buf + N;                         // N

    hipMemsetAsync(ws, 0, 64 + (size_t)N * sizeof(int), stream);  // stats + cnt

    const int B = 256;
    const int NB = (N + 255) / 256;

    k_softmax<<<(N * CN + B - 1) / B, B, 0, stream>>>(logits, probs, N);

    k_hist<<<(E + B - 1) / B, B, 0, stream>>>(dst, cnt, E);
    k_blocksum<<<NB, 256, 0, stream>>>(cnt, bsum, N);
    k_scanb<<<1, 512, 0, stream>>>(bsum, bscan, NB);
    k_offsets<<<NB, 256, 0, stream>>>(cnt, bscan, off, cur, N);
    k_fill<<<(E + B - 1) / B, B, 0, stream>>>(src, dst, cur, eidx, E);

    k_probs_f<<<(N * CN + B - 1) / B, B, 0, stream>>>(probs, off, cnt, eidx, f1buf, f2buf, stats, N);
    k_z<<<(N + B - 1) / B, B, 0, stream>>>(f1buf, f2buf, stats, old_z, tau1, tau2, z_out, gate, N);

    k_gather_final<<<(N * 64 + B - 1) / B, B, 0, stream>>>(h, off, cnt, eidx, gate, norm, out, N);
}

// Round 3
// 941.106 us; speedup vs baseline: 3.1825x; 1.0124x over previous
//
#include <hip/hip_runtime.h>
#include <math.h>

#define CN 32    // classes
#define DN 128   // feature dim

// ---------------- softmax over C per node: 32 threads/node ----------------
__global__ void k_softmax(const float* __restrict__ logits, float* __restrict__ probs, int N) {
    int t = blockIdx.x * blockDim.x + threadIdx.x;
    int node = t >> 5, c = t & 31;
    if (node >= N) return;
    float l = logits[node * CN + c];
    float m = l;
    #pragma unroll
    for (int o = 16; o; o >>= 1) m = fmaxf(m, __shfl_xor(m, o, 32));
    float e = __expf(l - m);
    float s = e;
    #pragma unroll
    for (int o = 16; o; o >>= 1) s += __shfl_xor(s, o, 32);
    probs[node * CN + c] = e / s;
}

// ---------------- CSR build: histogram of dst ----------------
__global__ void k_hist(const int* __restrict__ dst, int* __restrict__ cnt, int E) {
    int e = blockIdx.x * blockDim.x + threadIdx.x;
    if (e < E) atomicAdd(&cnt[dst[e]], 1);
}

// per-256-block sums of cnt
__global__ void k_blocksum(const int* __restrict__ cnt, int* __restrict__ bsum, int N) {
    int i = blockIdx.x * 256 + threadIdx.x;
    int v = (i < N) ? cnt[i] : 0;
    #pragma unroll
    for (int o = 32; o; o >>= 1) v += __shfl_down(v, o, 64);
    __shared__ int sh[4];
    int wv = threadIdx.x >> 6, ln = threadIdx.x & 63;
    if (ln == 0) sh[wv] = v;
    __syncthreads();
    if (threadIdx.x == 0) bsum[blockIdx.x] = sh[0] + sh[1] + sh[2] + sh[3];
}

// single-block exclusive scan of block sums (NB <= 512)
__global__ void k_scanb(const int* __restrict__ bsum, int* __restrict__ bscan, int NB) {
    int t = threadIdx.x;
    int v = (t < NB) ? bsum[t] : 0;
    int incl = v;
    int ln = t & 63;
    #pragma unroll
    for (int o = 1; o < 64; o <<= 1) { int u = __shfl_up(incl, o, 64); if (ln >= o) incl += u; }
    __shared__ int wsum[8];
    int wv = t >> 6;
    if (ln == 63) wsum[wv] = incl;
    __syncthreads();
    int add = 0;
    for (int w = 0; w < wv; ++w) add += wsum[w];
    if (t < NB) bscan[t] = incl - v + add;
}

// per-element exclusive offsets = local scan + bscan[block]; also init cursors
__global__ void k_offsets(const int* __restrict__ cnt, const int* __restrict__ bscan,
                          int* __restrict__ off, int* __restrict__ cur, int N) {
    int i = blockIdx.x * 256 + threadIdx.x;
    int v = (i < N) ? cnt[i] : 0;
    int ln = threadIdx.x & 63, wv = threadIdx.x >> 6;
    int incl = v;
    #pragma unroll
    for (int o = 1; o < 64; o <<= 1) { int u = __shfl_up(incl, o, 64); if (ln >= o) incl += u; }
    __shared__ int wsum[4];
    if (ln == 63) wsum[wv] = incl;
    __syncthreads();
    int add = bscan[blockIdx.x];
    for (int w = 0; w < wv; ++w) add += wsum[w];
    if (i < N) { int ex = incl - v + add; off[i] = ex; cur[i] = ex; }
}

// bucket-fill edge sources by dst
__global__ void k_fill(const int* __restrict__ src, const int* __restrict__ dst,
                       int* __restrict__ cur, int* __restrict__ eidx, int E) {
    int e = blockIdx.x * blockDim.x + threadIdx.x;
    if (e >= E) return;
    int p = atomicAdd(&cur[dst[e]], 1);
    eidx[p] = src[e];
}

// ---- gather probs + KL/entropy + global LN stats: 32 threads/node ----
// MLP trick: load 32 neighbor indices with ONE coalesced load, shfl-broadcast,
// then issue 32 independent row gathers (branch-free, predicated adds).
__global__ void k_probs_f(const float* __restrict__ probs, const int* __restrict__ off,
                          const int* __restrict__ cnt, const int* __restrict__ eidx,
                          float* __restrict__ f1buf, float* __restrict__ f2buf,
                          double* __restrict__ stats, int N) {
    int t = blockIdx.x * blockDim.x + threadIdx.x;
    int i = t >> 5, c = t & 31;
    float f1 = 0.f, f2 = 0.f;
    if (i < N) {
        int beg = off[i], dg = cnt[i];
        float sum = 0.f;
        for (int base = 0; base < dg; base += 32) {
            int rem = dg - base;                       // > 0, uniform in group
            int myi = (c < rem) ? eidx[beg + base + c] : 0;
            #pragma unroll
            for (int j = 0; j < 32; ++j) {
                int s = __shfl(myi, j, 32);
                float v = probs[(size_t)s * CN + c];   // always issued; row 0 if padded
                sum += (j < rem) ? v : 0.f;
            }
        }
        float f1c = 0.f, f2c = 0.f;
        if (dg > 0) {
            float p = probs[(size_t)i * CN + c];
            float mp = sum / (float)dg;
            float lm = logf(mp + 1e-9f);
            f1c = p * (logf(p + 1e-9f) - lm);
            f2c = -mp * lm;
        }
        #pragma unroll
        for (int o = 16; o; o >>= 1) { f1c += __shfl_xor(f1c, o, 32); f2c += __shfl_xor(f2c, o, 32); }
        if (c == 0) { f1buf[i] = f1c; f2buf[i] = f2c; f1 = f1c; f2 = f2c; }
    }
    // block reduction of (f1, f1^2, f2, f2^2) in double; nonzero only on c==0 lanes
    double v0 = f1, v1 = (double)f1 * f1, v2 = f2, v3 = (double)f2 * f2;
    #pragma unroll
    for (int o = 32; o; o >>= 1) {
        v0 += __shfl_down(v0, o, 64);
        v1 += __shfl_down(v1, o, 64);
        v2 += __shfl_down(v2, o, 64);
        v3 += __shfl_down(v3, o, 64);
    }
    __shared__ double sh[4][4];
    int wave = threadIdx.x >> 6, lane = threadIdx.x & 63;
    if (lane == 0) { sh[0][wave] = v0; sh[1][wave] = v1; sh[2][wave] = v2; sh[3][wave] = v3; }
    __syncthreads();
    if (threadIdx.x == 0) {
        double a = 0, b = 0, c2 = 0, d = 0;
        #pragma unroll
        for (int w = 0; w < 4; ++w) { a += sh[0][w]; b += sh[1][w]; c2 += sh[2][w]; d += sh[3][w]; }
        atomicAdd(&stats[0], a);
        atomicAdd(&stats[1], b);
        atomicAdd(&stats[2], c2);
        atomicAdd(&stats[3], d);
    }
}

// ---------------- per-node gating: z, gate = min(old_z, z) ----------------
__global__ void k_z(const float* __restrict__ f1buf, const float* __restrict__ f2buf,
                    const double* __restrict__ stats, const float* __restrict__ old_z,
                    const float* __restrict__ tau1, const float* __restrict__ tau2,
                    float* __restrict__ z_out, float* __restrict__ gate, int N) {
    int i = blockIdx.x * blockDim.x + threadIdx.x;
    if (i >= N) return;
    double invN = 1.0 / (double)N;
    float mu1 = (float)(stats[0] * invN);
    float var1 = (float)(stats[1] * invN) - mu1 * mu1;
    float is1 = rsqrtf(var1 + 1e-5f);
    float mu2 = (float)(stats[2] * invN);
    float var2 = (float)(stats[3] * invN) - mu2 * mu2;
    float is2 = rsqrtf(var2 + 1e-5f);
    float a = (f1buf[i] - mu1) * is1;
    float b = (f2buf[i] - mu2) * is2;
    float z = (1.f / (1.f + __expf(a - tau1[0]))) * (1.f / (1.f + __expf(b - tau2[0])));
    z_out[i] = z;
    gate[i] = fminf(old_z[i], z);
}

// ---- gather h + epilogue: one wave per node, float2 per lane ----
// Same MLP trick: 32 indices per coalesced load (lanes 0..31), shfl over wave,
// 32 independent float2 row loads in flight.
__global__ void k_gather_final(const float* __restrict__ h, const int* __restrict__ off,
                               const int* __restrict__ cnt, const int* __restrict__ eidx,
                               const float* __restrict__ gate, const float* __restrict__ norm,
                               float* __restrict__ out, int N) {
    int t = blockIdx.x * blockDim.x + threadIdx.x;
    int i = t >> 6, ln = t & 63;
    if (i >= N) return;
    int beg = off[i], dg = cnt[i];
    const float2* h2 = (const float2*)h;
    float ax = 0.f, ay = 0.f;
    for (int base = 0; base < dg; base += 32) {
        int rem = dg - base;                           // > 0, wave-uniform
        int lim = rem < 32 ? rem : 32;
        int myi = (ln < lim) ? eidx[beg + base + ln] : 0;   // lanes 0..31 supply idx
        #pragma unroll
        for (int j = 0; j < 32; ++j) {
            int s = __shfl(myi, j, 64);
            float2 v = h2[(size_t)s * 64 + ln];        // always issued; row 0 if padded
            bool use = j < rem;
            ax += use ? v.x : 0.f;
            ay += use ? v.y : 0.f;
        }
    }
    float g = gate[i], nm = norm[i];
    float2 hv = h2[(size_t)i * 64 + ln];
    float2 r;
    r.x = hv.x + g * fmaxf(ax * nm, 0.f);
    r.y = hv.y + g * fmaxf(ay * nm, 0.f);
    ((float2*)out)[(size_t)i * 64 + ln] = r;
}

extern "C" void kernel_launch(void* const* d_in, const int* in_sizes, int n_in,
                              void* d_out, int out_size, void* d_ws, size_t ws_size,
                              hipStream_t stream) {
    const float* h      = (const float*)d_in[0];
    const float* logits = (const float*)d_in[1];
    const float* old_z  = (const float*)d_in[2];
    const float* norm   = (const float*)d_in[3];
    const float* tau1   = (const float*)d_in[4];
    const float* tau2   = (const float*)d_in[5];
    const int*   src    = (const int*)d_in[6];
    const int*   dst    = (const int*)d_in[7];
    const int N = in_sizes[2];   // old_z length
    const int E = in_sizes[6];   // src length

    float* out   = (float*)d_out;            // [N*DN] new_h, then [N] z
    float* z_out = out + (size_t)N * DN;

    // workspace layout
    char*   ws    = (char*)d_ws;
    double* stats = (double*)ws;                       // 4 doubles (pad to 64B)
    int*    cnt   = (int*)(ws + 64);                   // N
    int*    off   = cnt + N;                           // N
    int*    cur   = off + N;                           // N
    int*    bsum  = cur + N;                           // 512
    int*    bscan = bsum + 512;                        // 512
    int*    eidx  = bscan + 512;                       // E
    float*  probs = (float*)(eidx + E);                // N*CN
    float*  f1buf = probs + (size_t)N * CN;            // N
    float*  f2buf = f1buf + N;                         // N
    float*  gate  = f2buf + N;                         // N

    hipMemsetAsync(ws, 0, 64 + (size_t)N * sizeof(int), stream);  // stats + cnt

    const int B = 256;
    const int NB = (N + 255) / 256;

    k_softmax<<<(N * CN + B - 1) / B, B, 0, stream>>>(logits, probs, N);

    k_hist<<<(E + B - 1) / B, B, 0, stream>>>(dst, cnt, E);
    k_blocksum<<<NB, 256, 0, stream>>>(cnt, bsum, N);
    k_scanb<<<1, 512, 0, stream>>>(bsum, bscan, NB);
    k_offsets<<<NB, 256, 0, stream>>>(cnt, bscan, off, cur, N);
    k_fill<<<(E + B - 1) / B, B, 0, stream>>>(src, dst, cur, eidx, E);

    k_probs_f<<<(N * CN + B - 1) / B, B, 0, stream>>>(probs, off, cnt, eidx, f1buf, f2buf, stats, N);
    k_z<<<(N + B - 1) / B, B, 0, stream>>>(f1buf, f2buf, stats, old_z, tau1, tau2, z_out, gate, N);

    k_gather_final<<<(N * 64 + B - 1) / B, B, 0, stream>>>(h, off, cnt, eidx, gate, norm, out, N);
}

// Round 4
// 398.228 us; speedup vs baseline: 7.5210x; 2.3632x over previous
//
#include <hip/hip_runtime.h>
#include <math.h>

#define CN 32    // classes
#define DN 128   // feature dim

// ---------------- softmax over C per node: 32 threads/node ----------------
__global__ void k_softmax(const float* __restrict__ logits, float* __restrict__ probs, int N) {
    int t = blockIdx.x * blockDim.x + threadIdx.x;
    int node = t >> 5, c = t & 31;
    if (node >= N) return;
    float l = logits[node * CN + c];
    float m = l;
    #pragma unroll
    for (int o = 16; o; o >>= 1) m = fmaxf(m, __shfl_xor(m, o, 32));
    float e = __expf(l - m);
    float s = e;
    #pragma unroll
    for (int o = 16; o; o >>= 1) s += __shfl_xor(s, o, 32);
    probs[node * CN + c] = e / s;
}

// ---------------- CSR build: histogram of dst ----------------
__global__ void k_hist(const int* __restrict__ dst, int* __restrict__ cnt, int E) {
    int e = blockIdx.x * blockDim.x + threadIdx.x;
    if (e < E) atomicAdd(&cnt[dst[e]], 1);
}

// per-256-block sums of cnt
__global__ void k_blocksum(const int* __restrict__ cnt, int* __restrict__ bsum, int N) {
    int i = blockIdx.x * 256 + threadIdx.x;
    int v = (i < N) ? cnt[i] : 0;
    #pragma unroll
    for (int o = 32; o; o >>= 1) v += __shfl_down(v, o, 64);
    __shared__ int sh[4];
    int wv = threadIdx.x >> 6, ln = threadIdx.x & 63;
    if (ln == 0) sh[wv] = v;
    __syncthreads();
    if (threadIdx.x == 0) bsum[blockIdx.x] = sh[0] + sh[1] + sh[2] + sh[3];
}

// single-block exclusive scan of block sums (NB <= 512)
__global__ void k_scanb(const int* __restrict__ bsum, int* __restrict__ bscan, int NB) {
    int t = threadIdx.x;
    int v = (t < NB) ? bsum[t] : 0;
    int incl = v;
    int ln = t & 63;
    #pragma unroll
    for (int o = 1; o < 64; o <<= 1) { int u = __shfl_up(incl, o, 64); if (ln >= o) incl += u; }
    __shared__ int wsum[8];
    int wv = t >> 6;
    if (ln == 63) wsum[wv] = incl;
    __syncthreads();
    int add = 0;
    for (int w = 0; w < wv; ++w) add += wsum[w];
    if (t < NB) bscan[t] = incl - v + add;
}

// per-element exclusive offsets = local scan + bscan[block]; also init cursors
__global__ void k_offsets(const int* __restrict__ cnt, const int* __restrict__ bscan,
                          int* __restrict__ off, int* __restrict__ cur, int N) {
    int i = blockIdx.x * 256 + threadIdx.x;
    int v = (i < N) ? cnt[i] : 0;
    int ln = threadIdx.x & 63, wv = threadIdx.x >> 6;
    int incl = v;
    #pragma unroll
    for (int o = 1; o < 64; o <<= 1) { int u = __shfl_up(incl, o, 64); if (ln >= o) incl += u; }
    __shared__ int wsum[4];
    if (ln == 63) wsum[wv] = incl;
    __syncthreads();
    int add = bscan[blockIdx.x];
    for (int w = 0; w < wv; ++w) add += wsum[w];
    if (i < N) { int ex = incl - v + add; off[i] = ex; cur[i] = ex; }
}

// bucket-fill edge sources by dst
__global__ void k_fill(const int* __restrict__ src, const int* __restrict__ dst,
                       int* __restrict__ cur, int* __restrict__ eidx, int E) {
    int e = blockIdx.x * blockDim.x + threadIdx.x;
    if (e >= E) return;
    int p = atomicAdd(&cur[dst[e]], 1);
    eidx[p] = src[e];
}

// ---- gather probs + KL/entropy + per-block LN partials: 32 threads/node ----
// NO contended atomics: block partial (f1,f1^2,f2,f2^2) stored to pbuf[blk].
__global__ void k_probs_f(const float* __restrict__ probs, const int* __restrict__ off,
                          const int* __restrict__ cnt, const int* __restrict__ eidx,
                          float* __restrict__ f1buf, float* __restrict__ f2buf,
                          double* __restrict__ pbuf, int N) {
    int t = blockIdx.x * blockDim.x + threadIdx.x;
    int i = t >> 5, c = t & 31;
    float f1 = 0.f, f2 = 0.f;
    if (i < N) {
        int beg = off[i], dg = cnt[i];
        float sum = 0.f;
        for (int base = 0; base < dg; base += 16) {
            int rem = dg - base;                       // > 0, uniform in group
            int lim = rem < 16 ? rem : 16;
            int myi = (c < lim) ? eidx[beg + base + c] : 0;  // lanes 0..15 supply idx
            #pragma unroll
            for (int j = 0; j < 16; ++j) {
                int s = __shfl(myi, j, 32);
                float v = probs[(size_t)s * CN + c];   // always issued; row 0 if padded
                sum += (j < rem) ? v : 0.f;
            }
        }
        float f1c = 0.f, f2c = 0.f;
        if (dg > 0) {
            float p = probs[(size_t)i * CN + c];
            float mp = sum / (float)dg;
            float lm = logf(mp + 1e-9f);
            f1c = p * (logf(p + 1e-9f) - lm);
            f2c = -mp * lm;
        }
        #pragma unroll
        for (int o = 16; o; o >>= 1) { f1c += __shfl_xor(f1c, o, 32); f2c += __shfl_xor(f2c, o, 32); }
        if (c == 0) { f1buf[i] = f1c; f2buf[i] = f2c; f1 = f1c; f2 = f2c; }
    }
    // block reduction of (f1, f1^2, f2, f2^2) in double; nonzero only on c==0 lanes
    double v0 = f1, v1 = (double)f1 * f1, v2 = f2, v3 = (double)f2 * f2;
    #pragma unroll
    for (int o = 32; o; o >>= 1) {
        v0 += __shfl_down(v0, o, 64);
        v1 += __shfl_down(v1, o, 64);
        v2 += __shfl_down(v2, o, 64);
        v3 += __shfl_down(v3, o, 64);
    }
    __shared__ double sh[4][4];
    int wave = threadIdx.x >> 6, lane = threadIdx.x & 63;
    if (lane == 0) { sh[0][wave] = v0; sh[1][wave] = v1; sh[2][wave] = v2; sh[3][wave] = v3; }
    __syncthreads();
    if (threadIdx.x == 0) {
        double a = 0, b = 0, c2 = 0, d = 0;
        #pragma unroll
        for (int w = 0; w < 4; ++w) { a += sh[0][w]; b += sh[1][w]; c2 += sh[2][w]; d += sh[3][w]; }
        double* p = pbuf + (size_t)blockIdx.x * 4;
        p[0] = a; p[1] = b; p[2] = c2; p[3] = d;
    }
}

// ---- deterministic single-block reduction of block partials -> stats ----
__global__ void k_redstats(const double* __restrict__ pbuf, double* __restrict__ stats, int nblk) {
    int t = threadIdx.x;
    double a = 0, b = 0, c = 0, d = 0;
    for (int k = t; k < nblk; k += blockDim.x) {
        const double* p = pbuf + (size_t)k * 4;
        a += p[0]; b += p[1]; c += p[2]; d += p[3];
    }
    #pragma unroll
    for (int o = 32; o; o >>= 1) {
        a += __shfl_down(a, o, 64);
        b += __shfl_down(b, o, 64);
        c += __shfl_down(c, o, 64);
        d += __shfl_down(d, o, 64);
    }
    __shared__ double sh[4][16];
    int wv = t >> 6, ln = t & 63;
    if (ln == 0) { sh[0][wv] = a; sh[1][wv] = b; sh[2][wv] = c; sh[3][wv] = d; }
    __syncthreads();
    if (t == 0) {
        double s0 = 0, s1 = 0, s2 = 0, s3 = 0;
        int nw = blockDim.x >> 6;
        for (int w = 0; w < nw; ++w) { s0 += sh[0][w]; s1 += sh[1][w]; s2 += sh[2][w]; s3 += sh[3][w]; }
        stats[0] = s0; stats[1] = s1; stats[2] = s2; stats[3] = s3;
    }
}

// ---------------- per-node gating: z, gate = min(old_z, z) ----------------
__global__ void k_z(const float* __restrict__ f1buf, const float* __restrict__ f2buf,
                    const double* __restrict__ stats, const float* __restrict__ old_z,
                    const float* __restrict__ tau1, const float* __restrict__ tau2,
                    float* __restrict__ z_out, float* __restrict__ gate, int N) {
    int i = blockIdx.x * blockDim.x + threadIdx.x;
    if (i >= N) return;
    double invN = 1.0 / (double)N;
    float mu1 = (float)(stats[0] * invN);
    float var1 = (float)(stats[1] * invN) - mu1 * mu1;
    float is1 = rsqrtf(var1 + 1e-5f);
    float mu2 = (float)(stats[2] * invN);
    float var2 = (float)(stats[3] * invN) - mu2 * mu2;
    float is2 = rsqrtf(var2 + 1e-5f);
    float a = (f1buf[i] - mu1) * is1;
    float b = (f2buf[i] - mu2) * is2;
    float z = (1.f / (1.f + __expf(a - tau1[0]))) * (1.f / (1.f + __expf(b - tau2[0])));
    z_out[i] = z;
    gate[i] = fminf(old_z[i], z);
}

// ---- gather h + epilogue: one wave per node, float2 per lane ----
__global__ void k_gather_final(const float* __restrict__ h, const int* __restrict__ off,
                               const int* __restrict__ cnt, const int* __restrict__ eidx,
                               const float* __restrict__ gate, const float* __restrict__ norm,
                               float* __restrict__ out, int N) {
    int t = blockIdx.x * blockDim.x + threadIdx.x;
    int i = t >> 6, ln = t & 63;
    if (i >= N) return;
    int beg = off[i], dg = cnt[i];
    const float2* h2 = (const float2*)h;
    float ax = 0.f, ay = 0.f;
    for (int base = 0; base < dg; base += 16) {
        int rem = dg - base;                           // > 0, wave-uniform
        int lim = rem < 16 ? rem : 16;
        int myi = (ln < lim) ? eidx[beg + base + ln] : 0;   // lanes 0..15 supply idx
        #pragma unroll
        for (int j = 0; j < 16; ++j) {
            int s = __shfl(myi, j, 64);
            float2 v = h2[(size_t)s * 64 + ln];        // always issued; row 0 if padded
            bool use = j < rem;
            ax += use ? v.x : 0.f;
            ay += use ? v.y : 0.f;
        }
    }
    float g = gate[i], nm = norm[i];
    float2 hv = h2[(size_t)i * 64 + ln];
    float2 r;
    r.x = hv.x + g * fmaxf(ax * nm, 0.f);
    r.y = hv.y + g * fmaxf(ay * nm, 0.f);
    ((float2*)out)[(size_t)i * 64 + ln] = r;
}

extern "C" void kernel_launch(void* const* d_in, const int* in_sizes, int n_in,
                              void* d_out, int out_size, void* d_ws, size_t ws_size,
                              hipStream_t stream) {
    const float* h      = (const float*)d_in[0];
    const float* logits = (const float*)d_in[1];
    const float* old_z  = (const float*)d_in[2];
    const float* norm   = (const float*)d_in[3];
    const float* tau1   = (const float*)d_in[4];
    const float* tau2   = (const float*)d_in[5];
    const int*   src    = (const int*)d_in[6];
    const int*   dst    = (const int*)d_in[7];
    const int N = in_sizes[2];   // old_z length
    const int E = in_sizes[6];   // src length

    float* out   = (float*)d_out;            // [N*DN] new_h, then [N] z
    float* z_out = out + (size_t)N * DN;

    const int B = 256;
    const int NB = (N + 255) / 256;
    const int NBF = (N * CN + B - 1) / B;     // blocks of k_probs_f

    // workspace layout
    char*   ws    = (char*)d_ws;
    double* stats = (double*)ws;                       // 4 doubles (pad to 64B)
    int*    cnt   = (int*)(ws + 64);                   // N
    int*    off   = cnt + N;                           // N
    int*    cur   = off + N;                           // N
    int*    bsum  = cur + N;                           // 512
    int*    bscan = bsum + 512;                        // 512
    int*    eidx  = bscan + 512;                       // E
    float*  probs = (float*)(eidx + E);                // N*CN
    float*  f1buf = probs + (size_t)N * CN;            // N
    float*  f2buf = f1buf + N;                         // N
    float*  gate  = f2buf + N;                         // N
    double* pbuf  = (double*)(((size_t)(gate + N) + 15) & ~(size_t)15);  // NBF*4 doubles

    hipMemsetAsync(cnt, 0, (size_t)N * sizeof(int), stream);

    k_softmax<<<(N * CN + B - 1) / B, B, 0, stream>>>(logits, probs, N);

    k_hist<<<(E + B - 1) / B, B, 0, stream>>>(dst, cnt, E);
    k_blocksum<<<NB, 256, 0, stream>>>(cnt, bsum, N);
    k_scanb<<<1, 512, 0, stream>>>(bsum, bscan, NB);
    k_offsets<<<NB, 256, 0, stream>>>(cnt, bscan, off, cur, N);
    k_fill<<<(E + B - 1) / B, B, 0, stream>>>(src, dst, cur, eidx, E);

    k_probs_f<<<NBF, B, 0, stream>>>(probs, off, cnt, eidx, f1buf, f2buf, pbuf, N);
    k_redstats<<<1, 1024, 0, stream>>>(pbuf, stats, NBF);
    k_z<<<(N + B - 1) / B, B, 0, stream>>>(f1buf, f2buf, stats, old_z, tau1, tau2, z_out, gate, N);

    k_gather_final<<<(N * 64 + B - 1) / B, B, 0, stream>>>(h, off, cnt, eidx, gate, norm, out, N);
}

// Round 5
// 302.698 us; speedup vs baseline: 9.8946x; 1.3156x over previous
//
#include <hip/hip_runtime.h>
#include <math.h>

#define CN 32    // classes
#define DN 128   // feature dim
#define BKT_SHIFT 9          // 512 nodes per bucket
#define BKT_NODES 512
#define CHUNK 8192           // edges per partition chunk (32 per thread, 256 threads)
#define MAXBKT 1024

// ---------------- softmax over C per node: 32 threads/node ----------------
__global__ void k_softmax(const float* __restrict__ logits, float* __restrict__ probs, int N) {
    int t = blockIdx.x * blockDim.x + threadIdx.x;
    int node = t >> 5, c = t & 31;
    if (node >= N) return;
    float l = logits[node * CN + c];
    float m = l;
    #pragma unroll
    for (int o = 16; o; o >>= 1) m = fmaxf(m, __shfl_xor(m, o, 32));
    float e = __expf(l - m);
    float s = e;
    #pragma unroll
    for (int o = 16; o; o >>= 1) s += __shfl_xor(s, o, 32);
    probs[node * CN + c] = e / s;
}

// ---- pass A: per-chunk bucket histogram. grid = NCH x 256 ----
__global__ void k_part_hist(const int* __restrict__ dst, int* __restrict__ M,
                            int E, int NBKT) {
    __shared__ int hist[MAXBKT];
    int t = threadIdx.x;
    for (int j = t; j < NBKT; j += 256) hist[j] = 0;
    __syncthreads();
    int ebeg = blockIdx.x * CHUNK;
    #pragma unroll
    for (int k = 0; k < CHUNK / 256; ++k) {
        int e = ebeg + k * 256 + t;
        if (e < E) atomicAdd(&hist[dst[e] >> BKT_SHIFT], 1);
    }
    __syncthreads();
    int* row = M + (size_t)blockIdx.x * NBKT;
    for (int j = t; j < NBKT; j += 256) row[j] = hist[j];
}

// ---- pass B: exclusive scan of M in bucket-major order (k = b*NCH + ch,
// stored at M[ch*NBKT + b]); single block of 1024 threads. bbase[b] = bucket start.
__global__ void k_part_scan(int* __restrict__ M, int* __restrict__ bbase,
                            int NCH, int NBKT, int E) {
    __shared__ int wsum[16], wpre[16];
    __shared__ int carry;
    int t = threadIdx.x, ln = t & 63, wv = t >> 6;
    if (t == 0) carry = 0;
    __syncthreads();
    int L = NCH * NBKT;
    for (int base = 0; base < L; base += 1024) {
        int k = base + t;
        int idx = 0, v = 0;
        if (k < L) {
            int b = k / NCH, ch = k - b * NCH;
            idx = ch * NBKT + b;
            v = M[idx];
        }
        int incl = v;
        #pragma unroll
        for (int o = 1; o < 64; o <<= 1) { int u = __shfl_up(incl, o, 64); if (ln >= o) incl += u; }
        if (ln == 63) wsum[wv] = incl;
        __syncthreads();
        if (t == 0) {
            int r = carry;
            #pragma unroll
            for (int w = 0; w < 16; ++w) { wpre[w] = r; r += wsum[w]; }
            carry = r;
        }
        __syncthreads();
        if (k < L) M[idx] = wpre[wv] + incl - v;
        __syncthreads();
    }
    for (int b = t; b < NBKT; b += 1024) bbase[b] = M[b];   // idx=b is (bucket b, chunk 0)
    if (t == 0) bbase[NBKT] = E;
}

// ---- pass C: partition edges into bucket-major slices, packed (local<<17)|src ----
__global__ void k_part_scatter(const int* __restrict__ src, const int* __restrict__ dst,
                               const int* __restrict__ M, int* __restrict__ part,
                               int E, int NBKT) {
    __shared__ int cur[MAXBKT];
    int t = threadIdx.x;
    const int* row = M + (size_t)blockIdx.x * NBKT;
    for (int j = t; j < NBKT; j += 256) cur[j] = row[j];
    __syncthreads();
    int ebeg = blockIdx.x * CHUNK;
    #pragma unroll
    for (int k = 0; k < CHUNK / 256; ++k) {
        int e = ebeg + k * 256 + t;
        if (e < E) {
            int d = dst[e];
            int b = d >> BKT_SHIFT;
            int p = atomicAdd(&cur[b], 1);
            part[p] = ((d & (BKT_NODES - 1)) << 17) | src[e];
        }
    }
}

// ---- pass D: per-bucket LDS counting sort -> cnt, off, eidx. grid = NBKT x 512 ----
__global__ void k_bucket_csr(const int* __restrict__ part, const int* __restrict__ bbase,
                             int* __restrict__ cnt, int* __restrict__ off,
                             int* __restrict__ eidx, int N) {
    __shared__ int hcnt[BKT_NODES];
    __shared__ int wsum[8], wpre[8];
    int t = threadIdx.x, ln = t & 63, wv = t >> 6;
    int b = blockIdx.x;
    int lo = bbase[b], hi = bbase[b + 1];
    hcnt[t] = 0;
    __syncthreads();
    for (int e = lo + t; e < hi; e += BKT_NODES)
        atomicAdd(&hcnt[part[e] >> 17], 1);
    __syncthreads();
    int v = hcnt[t];
    int incl = v;
    #pragma unroll
    for (int o = 1; o < 64; o <<= 1) { int u = __shfl_up(incl, o, 64); if (ln >= o) incl += u; }
    if (ln == 63) wsum[wv] = incl;
    __syncthreads();
    if (t == 0) {
        int r = 0;
        #pragma unroll
        for (int w = 0; w < 8; ++w) { wpre[w] = r; r += wsum[w]; }
    }
    __syncthreads();
    int excl = wpre[wv] + incl - v;
    int g = b * BKT_NODES + t;
    if (g < N) { cnt[g] = v; off[g] = lo + excl; }
    hcnt[t] = excl;          // becomes per-node cursor
    __syncthreads();
    for (int e = lo + t; e < hi; e += BKT_NODES) {
        int pk = part[e];
        int p = atomicAdd(&hcnt[pk >> 17], 1);
        eidx[lo + p] = pk & 0x1FFFF;
    }
}

// ---- gather probs + KL/entropy + per-block LN partials: 32 threads/node ----
__global__ void k_probs_f(const float* __restrict__ probs, const int* __restrict__ off,
                          const int* __restrict__ cnt, const int* __restrict__ eidx,
                          float* __restrict__ f1buf, float* __restrict__ f2buf,
                          double* __restrict__ pbuf, int N) {
    int t = blockIdx.x * blockDim.x + threadIdx.x;
    int i = t >> 5, c = t & 31;
    float f1 = 0.f, f2 = 0.f;
    if (i < N) {
        int beg = off[i], dg = cnt[i];
        float sum = 0.f;
        for (int base = 0; base < dg; base += 16) {
            int rem = dg - base;                       // > 0, uniform in group
            int lim = rem < 16 ? rem : 16;
            int myi = (c < lim) ? eidx[beg + base + c] : 0;  // lanes 0..15 supply idx
            #pragma unroll
            for (int j = 0; j < 16; ++j) {
                int s = __shfl(myi, j, 32);
                float v = probs[(size_t)s * CN + c];   // always issued; row 0 if padded
                sum += (j < rem) ? v : 0.f;
            }
        }
        float f1c = 0.f, f2c = 0.f;
        if (dg > 0) {
            float p = probs[(size_t)i * CN + c];
            float mp = sum / (float)dg;
            float lm = logf(mp + 1e-9f);
            f1c = p * (logf(p + 1e-9f) - lm);
            f2c = -mp * lm;
        }
        #pragma unroll
        for (int o = 16; o; o >>= 1) { f1c += __shfl_xor(f1c, o, 32); f2c += __shfl_xor(f2c, o, 32); }
        if (c == 0) { f1buf[i] = f1c; f2buf[i] = f2c; f1 = f1c; f2 = f2c; }
    }
    // block reduction of (f1, f1^2, f2, f2^2) in double; nonzero only on c==0 lanes
    double v0 = f1, v1 = (double)f1 * f1, v2 = f2, v3 = (double)f2 * f2;
    #pragma unroll
    for (int o = 32; o; o >>= 1) {
        v0 += __shfl_down(v0, o, 64);
        v1 += __shfl_down(v1, o, 64);
        v2 += __shfl_down(v2, o, 64);
        v3 += __shfl_down(v3, o, 64);
    }
    __shared__ double sh[4][4];
    int wave = threadIdx.x >> 6, lane = threadIdx.x & 63;
    if (lane == 0) { sh[0][wave] = v0; sh[1][wave] = v1; sh[2][wave] = v2; sh[3][wave] = v3; }
    __syncthreads();
    if (threadIdx.x == 0) {
        double a = 0, b = 0, c2 = 0, d = 0;
        #pragma unroll
        for (int w = 0; w < 4; ++w) { a += sh[0][w]; b += sh[1][w]; c2 += sh[2][w]; d += sh[3][w]; }
        double* p = pbuf + (size_t)blockIdx.x * 4;
        p[0] = a; p[1] = b; p[2] = c2; p[3] = d;
    }
}

// ---- deterministic single-block reduction of block partials -> stats ----
__global__ void k_redstats(const double* __restrict__ pbuf, double* __restrict__ stats, int nblk) {
    int t = threadIdx.x;
    double a = 0, b = 0, c = 0, d = 0;
    for (int k = t; k < nblk; k += blockDim.x) {
        const double* p = pbuf + (size_t)k * 4;
        a += p[0]; b += p[1]; c += p[2]; d += p[3];
    }
    #pragma unroll
    for (int o = 32; o; o >>= 1) {
        a += __shfl_down(a, o, 64);
        b += __shfl_down(b, o, 64);
        c += __shfl_down(c, o, 64);
        d += __shfl_down(d, o, 64);
    }
    __shared__ double sh[4][16];
    int wv = t >> 6, ln = t & 63;
    if (ln == 0) { sh[0][wv] = a; sh[1][wv] = b; sh[2][wv] = c; sh[3][wv] = d; }
    __syncthreads();
    if (t == 0) {
        double s0 = 0, s1 = 0, s2 = 0, s3 = 0;
        int nw = blockDim.x >> 6;
        for (int w = 0; w < nw; ++w) { s0 += sh[0][w]; s1 += sh[1][w]; s2 += sh[2][w]; s3 += sh[3][w]; }
        stats[0] = s0; stats[1] = s1; stats[2] = s2; stats[3] = s3;
    }
}

// ---------------- per-node gating: z, gate = min(old_z, z) ----------------
__global__ void k_z(const float* __restrict__ f1buf, const float* __restrict__ f2buf,
                    const double* __restrict__ stats, const float* __restrict__ old_z,
                    const float* __restrict__ tau1, const float* __restrict__ tau2,
                    float* __restrict__ z_out, float* __restrict__ gate, int N) {
    int i = blockIdx.x * blockDim.x + threadIdx.x;
    if (i >= N) return;
    double invN = 1.0 / (double)N;
    float mu1 = (float)(stats[0] * invN);
    float var1 = (float)(stats[1] * invN) - mu1 * mu1;
    float is1 = rsqrtf(var1 + 1e-5f);
    float mu2 = (float)(stats[2] * invN);
    float var2 = (float)(stats[3] * invN) - mu2 * mu2;
    float is2 = rsqrtf(var2 + 1e-5f);
    float a = (f1buf[i] - mu1) * is1;
    float b = (f2buf[i] - mu2) * is2;
    float z = (1.f / (1.f + __expf(a - tau1[0]))) * (1.f / (1.f + __expf(b - tau2[0])));
    z_out[i] = z;
    gate[i] = fminf(old_z[i], z);
}

// ---- gather h + epilogue: one wave per node, float2 per lane ----
__global__ void k_gather_final(const float* __restrict__ h, const int* __restrict__ off,
                               const int* __restrict__ cnt, const int* __restrict__ eidx,
                               const float* __restrict__ gate, const float* __restrict__ norm,
                               float* __restrict__ out, int N) {
    int t = blockIdx.x * blockDim.x + threadIdx.x;
    int i = t >> 6, ln = t & 63;
    if (i >= N) return;
    int beg = off[i], dg = cnt[i];
    const float2* h2 = (const float2*)h;
    float ax = 0.f, ay = 0.f;
    for (int base = 0; base < dg; base += 16) {
        int rem = dg - base;                           // > 0, wave-uniform
        int lim = rem < 16 ? rem : 16;
        int myi = (ln < lim) ? eidx[beg + base + ln] : 0;   // lanes 0..15 supply idx
        #pragma unroll
        for (int j = 0; j < 16; ++j) {
            int s = __shfl(myi, j, 64);
            float2 v = h2[(size_t)s * 64 + ln];        // always issued; row 0 if padded
            bool use = j < rem;
            ax += use ? v.x : 0.f;
            ay += use ? v.y : 0.f;
        }
    }
    float g = gate[i], nm = norm[i];
    float2 hv = h2[(size_t)i * 64 + ln];
    float2 r;
    r.x = hv.x + g * fmaxf(ax * nm, 0.f);
    r.y = hv.y + g * fmaxf(ay * nm, 0.f);
    ((float2*)out)[(size_t)i * 64 + ln] = r;
}

extern "C" void kernel_launch(void* const* d_in, const int* in_sizes, int n_in,
                              void* d_out, int out_size, void* d_ws, size_t ws_size,
                              hipStream_t stream) {
    const float* h      = (const float*)d_in[0];
    const float* logits = (const float*)d_in[1];
    const float* old_z  = (const float*)d_in[2];
    const float* norm   = (const float*)d_in[3];
    const float* tau1   = (const float*)d_in[4];
    const float* tau2   = (const float*)d_in[5];
    const int*   src    = (const int*)d_in[6];
    const int*   dst    = (const int*)d_in[7];
    const int N = in_sizes[2];   // old_z length
    const int E = in_sizes[6];   // src length

    float* out   = (float*)d_out;            // [N*DN] new_h, then [N] z
    float* z_out = out + (size_t)N * DN;

    const int B = 256;
    const int NBF  = (N * CN + B - 1) / B;            // blocks of k_probs_f
    const int NBKT = (N + BKT_NODES - 1) >> BKT_SHIFT;
    const int NCH  = (E + CHUNK - 1) / CHUNK;

    // workspace layout
    char*   ws    = (char*)d_ws;
    double* stats = (double*)ws;                       // 4 doubles (pad to 64B)
    int*    cnt   = (int*)(ws + 64);                   // N
    int*    off   = cnt + N;                           // N
    int*    bbase = off + N;                           // NBKT+1 (pad MAXBKT+8)
    int*    M     = bbase + MAXBKT + 8;                // NCH*NBKT
    int*    eidx  = M + (size_t)NCH * NBKT;            // E
    int*    part  = eidx + E;                          // E
    float*  probs = (float*)(part + E);                // N*CN
    float*  f1buf = probs + (size_t)N * CN;            // N
    float*  f2buf = f1buf + N;                         // N
    float*  gate  = f2buf + N;                         // N
    double* pbuf  = (double*)(((size_t)(gate + N) + 15) & ~(size_t)15);  // NBF*4 doubles

    k_softmax<<<(N * CN + B - 1) / B, B, 0, stream>>>(logits, probs, N);

    k_part_hist<<<NCH, 256, 0, stream>>>(dst, M, E, NBKT);
    k_part_scan<<<1, 1024, 0, stream>>>(M, bbase, NCH, NBKT, E);
    k_part_scatter<<<NCH, 256, 0, stream>>>(src, dst, M, part, E, NBKT);
    k_bucket_csr<<<NBKT, BKT_NODES, 0, stream>>>(part, bbase, cnt, off, eidx, N);

    k_probs_f<<<NBF, B, 0, stream>>>(probs, off, cnt, eidx, f1buf, f2buf, pbuf, N);
    k_redstats<<<1, 1024, 0, stream>>>(pbuf, stats, NBF);
    k_z<<<(N + B - 1) / B, B, 0, stream>>>(f1buf, f2buf, stats, old_z, tau1, tau2, z_out, gate, N);

    k_gather_final<<<(N * 64 + B - 1) / B, B, 0, stream>>>(h, off, cnt, eidx, gate, norm, out, N);
}